// Round 5
// baseline (274.303 us; speedup 1.0000x reference)
//
#include <hip/hip_runtime.h>

// FEM stiffness matvec KU = sum_e scatter(K_type(e) @ gather(U, e)).
//
// Round 19 = R16 structure + type-half split K1: 2 blocks/CU with fp32 LDS.
// R18 post-mortem (124 us): global-K "L1 broadcast" theory WRONG - divergent
// per-lane float4 loads issue 144 VMEM transactions/elem, 32 KB L1 thrashes
// on a 147 KB table; VALUBusy fell 19->10 (more stall). Filters MUST be LDS.
// R17 lesson: LDS conflicts are not critical-path. R16 K1 is latency-bound
// at 16 waves/CU (148 KB LDS = 1 block/CU).
// R19 mechanism: block pair per 2048-elem window; even block = types 0-31,
// odd = types 32-63. Per-block LDS: 32-type fp32 table 73.7 KB (dynamic) +
// 6.4 KB sort/bucket = 80.1 KB < 81.9 -> 2 blocks x 1024 thr = 32 waves/CU
// (double latency hiding). Block-local sort (R17) keeps LDS reads uniform.
// Memory order preserved: nodIdx read within own 64 KB window (parity twin
// hits L2/L3), Ub gathered once per element, record runs ~270 B unchanged.
// RSHIFT 11->12 (245 buckets) shrinks bucket arrays to fit LDS; CAP 20480 =
// mean + 32 sigma. K2: 245 blocks x 48 KB sAcc (accepted small regression).
// HARD CONSTRAINT: 2048 resident threads need VGPR <= 64 ->
// launch_bounds(1024,8); R14 body measured 56, sort adds ~4. Watch
// VGPR_Count (R10: spill disaster mode).
// Carries: K2_TPB 1024, bf16-packed U, 8 B bf16 records, block tail
// reservation. R15: never permute elements globally. ~110 us harness fixed.

#define NTYPES    64
#define HTYPES    32             // types per parity block
#define KWORDS    576            // fp32 words per type (24*24), stride 576
#define RSHIFT    12
#define RNODES    4096
#define MAXB      256
#define CAP       20480          // mean 16327/bucket + 32 sigma (even)
#define K1_TPB    1024
#define WCHUNK    2048           // elements per window (block pair)
#define K2_TPB    1024
#define PREP_TPB  256

typedef int          nint4  __attribute__((ext_vector_type(4)));
typedef unsigned int nuint2 __attribute__((ext_vector_type(2)));
typedef unsigned int nuint4 __attribute__((ext_vector_type(4)));

__device__ __forceinline__ unsigned bf16_rne(float f) {
    unsigned b = __float_as_uint(f);
    return (b + 0x7FFFu + ((b >> 16) & 1u)) >> 16;
}

// ---- phase 0: pack U -> bf16 triples; zero KU and tails -------------------

__global__ __launch_bounds__(PREP_TPB) void pack_u_kernel(
    const float* __restrict__ U, nuint2* __restrict__ Ub,
    float* __restrict__ KU, unsigned* __restrict__ tails,
    int n_nodes, int n_buckets)
{
    int n = blockIdx.x * PREP_TPB + threadIdx.x;
    if (n < n_buckets) tails[n] = 0;
    if (n >= n_nodes) return;
    const float* up = U + (size_t)n * 3;
    unsigned bx = bf16_rne(up[0]);
    unsigned by = bf16_rne(up[1]);
    unsigned bz = bf16_rne(up[2]);
    nuint2 v = { bx | (by << 16), bz };
    Ub[n] = v;
    KU[3 * n + 0] = 0.f;
    KU[3 * n + 1] = 0.f;
    KU[3 * n + 2] = 0.f;
}

// ---- phase 1: compute + bin (type-half split, block-local sort) ----------

__global__ __launch_bounds__(K1_TPB, 8) void feconv_bin_kernel(
    const nuint2* __restrict__ Ub,      // [N] packed bf16 x,y,z
    const float* __restrict__ K,        // [64, 24, 24]
    const int*   __restrict__ types,    // [E]
    const int*   __restrict__ nodIdx,   // [E, 8]
    float*       __restrict__ KU,       // overflow fallback only
    unsigned*    __restrict__ tails,    // [n_buckets]
    nuint2*      __restrict__ recs,     // [n_buckets * CAP]
    int n_elems, int n_buckets)
{
    extern __shared__ float sK[];              // [HTYPES * KWORDS] = 73,728 B
    __shared__ unsigned       sCnt[MAXB];      // 1 KB
    __shared__ unsigned       sBase[MAXB];     // 1 KB
    __shared__ unsigned       sTCnt[HTYPES];   // 128 B
    __shared__ unsigned       sTOff[HTYPES];   // 128 B
    __shared__ unsigned short sOrder[WCHUNK];  // 4 KB: (rel<<11 | li)

    const int window = blockIdx.x >> 1;
    const int typeLo = (blockIdx.x & 1) * HTYPES;
    const int base   = window * WCHUNK;
    int cnt_chunk = n_elems - base;
    if (cnt_chunk > WCHUNK) cnt_chunk = WCHUNK;

    // stage this half's 32 filters: contiguous 73,728 B, fully coalesced
    for (int w = threadIdx.x; w < HTYPES * KWORDS; w += K1_TPB)
        sK[w] = K[(size_t)typeLo * KWORDS + w];
    for (int i = threadIdx.x; i < n_buckets; i += K1_TPB) sCnt[i] = 0;
    if (threadIdx.x < HTYPES) sTCnt[threadIdx.x] = 0;
    __syncthreads();

    // S0: coalesced type load; count only our half's types
    int myT[2];
#pragma unroll
    for (int k = 0; k < 2; ++k) {
        int li = threadIdx.x + k * K1_TPB;
        myT[k] = -1;
        if (li < cnt_chunk) {
            int rel = __builtin_nontemporal_load(&types[base + li]) - typeLo;
            if ((unsigned)rel < HTYPES) {
                myT[k] = rel;
                atomicAdd(&sTCnt[rel], 1u);
            }
        }
    }
    __syncthreads();

    // S1: exclusive prefix scan over 32 counts (lanes 0-31, shfl width 32)
    if (threadIdx.x < HTYPES) {
        unsigned v = sTCnt[threadIdx.x];
        unsigned s = v;
#pragma unroll
        for (int d = 1; d < HTYPES; d <<= 1) {
            unsigned o = __shfl_up(s, d, HTYPES);
            if ((int)threadIdx.x >= d) s += o;
        }
        sTOff[threadIdx.x] = s - v;
        sTCnt[threadIdx.x] = 0;          // reuse as placement cursor
    }
    __syncthreads();

    // S2: scatter into type-sorted order (packed: rel<<11 | local idx)
#pragma unroll
    for (int k = 0; k < 2; ++k) {
        if (myT[k] >= 0) {
            int li = threadIdx.x + k * K1_TPB;
            unsigned p = sTOff[myT[k]] + atomicAdd(&sTCnt[myT[k]], 1u);
            sOrder[p] = (unsigned short)(li | (myT[k] << 11));
        }
    }
    __syncthreads();

    const int cntHalf = (int)(sTOff[HTYPES - 1] + sTCnt[HTYPES - 1]);

    int    tt[2];
    int    nodes[2][8];
    nuint2 uu[2][8];                    // in-flight packed gathers

    // pass A: (sorted) connectivity + EARLY gather issue + bucket count.
    // nodIdx reads stay inside this window's 64 KB span (parity twin reads
    // the same lines -> L2/L3 hit); Ub gathered once per element chip-wide.
#pragma unroll
    for (int k = 0; k < 2; ++k) {
        int slot = threadIdx.x + k * K1_TPB;
        tt[k] = -1;
        if (slot < cntHalf) {
            unsigned od = sOrder[slot];
            int li  = od & (WCHUNK - 1);
            tt[k]   = od >> 11;
            int e   = base + li;
            const nint4* q = (const nint4*)(nodIdx + (size_t)e * 8);
            nint4 a = q[0];
            nint4 b = q[1];
            nodes[k][0] = a.x; nodes[k][1] = a.y; nodes[k][2] = a.z; nodes[k][3] = a.w;
            nodes[k][4] = b.x; nodes[k][5] = b.y; nodes[k][6] = b.z; nodes[k][7] = b.w;
#pragma unroll
            for (int j = 0; j < 8; ++j)
                uu[k][j] = Ub[nodes[k][j]];
#pragma unroll
            for (int j = 0; j < 8; ++j)
                atomicAdd(&sCnt[(unsigned)nodes[k][j] >> RSHIFT], 1u);
        }
    }
    __syncthreads();

    // pass B: one global tail reservation per (block, bucket)
    for (int b = threadIdx.x; b < n_buckets; b += K1_TPB) {
        unsigned c = sCnt[b];
        sBase[b] = c ? atomicAdd(&tails[b], c) : 0u;
        sCnt[b] = 0;                     // reuse as local cursor
    }
    __syncthreads();

    // pass C: unpack, matvec; sorted order -> ~wave-uniform LDS broadcasts
#pragma unroll
    for (int k = 0; k < 2; ++k) {
        if (tt[k] < 0) continue;

        float ue[24];
#pragma unroll
        for (int j = 0; j < 8; ++j) {
            nuint2 v = uu[k][j];
            ue[3 * j + 0] = __uint_as_float(v.x << 16);
            ue[3 * j + 1] = __uint_as_float(v.x & 0xFFFF0000u);
            ue[3 * j + 2] = __uint_as_float(v.y << 16);
        }

        const float4* Kt4 = (const float4*)(sK + (size_t)tt[k] * KWORDS);
#pragma unroll
        for (int j = 0; j < 8; ++j) {
            float a0 = 0.f, a1 = 0.f, a2 = 0.f;
#pragma unroll
            for (int q = 0; q < 6; ++q) {
                float4 k0 = Kt4[(3 * j + 0) * 6 + q];
                float4 k1 = Kt4[(3 * j + 1) * 6 + q];
                float4 k2 = Kt4[(3 * j + 2) * 6 + q];
                float u0 = ue[4 * q + 0], u1 = ue[4 * q + 1];
                float u2 = ue[4 * q + 2], u3 = ue[4 * q + 3];
                a0 += k0.x * u0 + k0.y * u1 + k0.z * u2 + k0.w * u3;
                a1 += k1.x * u0 + k1.y * u1 + k1.z * u2 + k1.w * u3;
                a2 += k2.x * u0 + k2.y * u1 + k2.z * u2 + k2.w * u3;
            }
            unsigned n = (unsigned)nodes[k][j];
            unsigned b = n >> RSHIFT;
            unsigned pos = sBase[b] + atomicAdd(&sCnt[b], 1u);
            if (pos < CAP) {
                unsigned local = n & (RNODES - 1);
                nuint2 r = { bf16_rne(a0) | (bf16_rne(a1) << 16),
                             bf16_rne(a2) | (local << 16) };
                recs[(size_t)b * CAP + pos] = r;
            } else {  // statistically unreachable; absolute correctness
                atomicAdd(&KU[(size_t)n * 3 + 0], a0);
                atomicAdd(&KU[(size_t)n * 3 + 1], a1);
                atomicAdd(&KU[(size_t)n * 3 + 2], a2);
            }
        }
    }
}

// ---- phase 2: accumulate per bucket --------------------------------------

__global__ __launch_bounds__(K2_TPB) void feconv_acc_kernel(
    const nuint2*   __restrict__ recs,
    const unsigned* __restrict__ tails,
    float*          __restrict__ KU,     // [N, 3], pre-zeroed
    int n_nodes)
{
    __shared__ float sAcc[RNODES * 3];   // 48 KB
    const int b = blockIdx.x;

    for (int i = threadIdx.x; i < RNODES * 3; i += K2_TPB) sAcc[i] = 0.f;
    __syncthreads();

    unsigned cnt = tails[b];
    if (cnt > CAP) cnt = CAP;
    const nuint2* base = recs + (size_t)b * CAP;
    const nuint4* base4 = (const nuint4*)base;       // 16 B-aligned (CAP even)

    unsigned npairs = cnt >> 1;
    for (unsigned i = threadIdx.x; i < npairs; i += K2_TPB) {
        nuint4 p = base4[i];                          // two records, one load
        unsigned o0 = (p.y >> 16) * 3;
        atomicAdd(&sAcc[o0 + 0], __uint_as_float(p.x << 16));
        atomicAdd(&sAcc[o0 + 1], __uint_as_float(p.x & 0xFFFF0000u));
        atomicAdd(&sAcc[o0 + 2], __uint_as_float(p.y << 16));
        unsigned o1 = (p.w >> 16) * 3;
        atomicAdd(&sAcc[o1 + 0], __uint_as_float(p.z << 16));
        atomicAdd(&sAcc[o1 + 1], __uint_as_float(p.z & 0xFFFF0000u));
        atomicAdd(&sAcc[o1 + 2], __uint_as_float(p.w << 16));
    }
    if ((cnt & 1u) && threadIdx.x == 0) {             // odd tail record
        nuint2 r = base[cnt - 1];
        unsigned o = (r.y >> 16) * 3;
        atomicAdd(&sAcc[o + 0], __uint_as_float(r.x << 16));
        atomicAdd(&sAcc[o + 1], __uint_as_float(r.x & 0xFFFF0000u));
        atomicAdd(&sAcc[o + 2], __uint_as_float(r.y << 16));
    }
    __syncthreads();

    const int nbase = b * RNODES;
    int limit = n_nodes - nbase;
    if (limit > RNODES) limit = RNODES;
    limit *= 3;
    float* out = KU + (size_t)nbase * 3;
    for (int i = threadIdx.x; i < limit; i += K2_TPB) out[i] += sAcc[i];
}

// ---- fallback (round-0 style) --------------------------------------------

__global__ __launch_bounds__(256) void feconv_elem_kernel(
    const float* __restrict__ U, const float* __restrict__ K,
    const int* __restrict__ types, const int* __restrict__ nodIdx,
    float* __restrict__ KU, int n_elems)
{
    int e = blockIdx.x * blockDim.x + threadIdx.x;
    if (e >= n_elems) return;
    int t = types[e];
    const int4* idx4 = (const int4*)(nodIdx + (size_t)e * 8);
    int4 iA = idx4[0], iB = idx4[1];
    int nodes[8] = {iA.x, iA.y, iA.z, iA.w, iB.x, iB.y, iB.z, iB.w};
    float ue[24];
#pragma unroll
    for (int j = 0; j < 8; ++j) {
        const float* up = U + (size_t)nodes[j] * 3;
        ue[3 * j + 0] = up[0]; ue[3 * j + 1] = up[1]; ue[3 * j + 2] = up[2];
    }
    const float* Kt = K + (size_t)t * 576;
#pragma unroll
    for (int i = 0; i < 24; ++i) {
        const float4* row = (const float4*)(Kt + i * 24);
        float acc = 0.f;
#pragma unroll
        for (int q = 0; q < 6; ++q) {
            float4 k = row[q];
            acc += k.x * ue[4 * q + 0] + k.y * ue[4 * q + 1]
                 + k.z * ue[4 * q + 2] + k.w * ue[4 * q + 3];
        }
        atomicAdd(&KU[(size_t)nodes[i / 3] * 3 + (i % 3)], acc);
    }
}

extern "C" void kernel_launch(void* const* d_in, const int* in_sizes, int n_in,
                              void* d_out, int out_size, void* d_ws, size_t ws_size,
                              hipStream_t stream) {
    const float* U      = (const float*)d_in[0];
    const float* Kf     = (const float*)d_in[1];
    const int*   types  = (const int*)d_in[2];
    const int*   nodIdx = (const int*)d_in[3];
    float*       KU     = (float*)d_out;

    const int n_elems = in_sizes[2];
    const int n_nodes = in_sizes[0] / 3;
    const int n_buckets = (n_nodes + RNODES - 1) / RNODES;   // 245 for N=1M

    // ws layout: [0, 4096) tails | [4096, +8B*n_nodes) Ub | then recs
    const size_t ub_off  = 4096;
    const size_t rec_off = ub_off + (((size_t)n_nodes * 8 + 255) & ~255ull);
    const size_t need    = rec_off + (size_t)n_buckets * CAP * 8;

    if (n_buckets <= MAXB && ws_size >= need) {
        unsigned* tails = (unsigned*)d_ws;
        nuint2*   Ub    = (nuint2*)((char*)d_ws + ub_off);
        nuint2*   recs  = (nuint2*)((char*)d_ws + rec_off);

        int gridP = (n_nodes + PREP_TPB - 1) / PREP_TPB;
        pack_u_kernel<<<gridP, PREP_TPB, 0, stream>>>(
            U, Ub, KU, tails, n_nodes, n_buckets);

        size_t lds_bytes = (size_t)HTYPES * KWORDS * sizeof(float); // 73,728
        int nWindows = (n_elems + WCHUNK - 1) / WCHUNK;             // 245
        int grid1 = nWindows * 2;                                   // 490
        feconv_bin_kernel<<<grid1, K1_TPB, lds_bytes, stream>>>(
            Ub, Kf, types, nodIdx, KU, tails, recs, n_elems, n_buckets);
        feconv_acc_kernel<<<n_buckets, K2_TPB, 0, stream>>>(
            recs, tails, KU, n_nodes);
    } else {
        (void)hipMemsetAsync(KU, 0, (size_t)out_size * sizeof(float), stream);
        int block = 256;
        int grid = (n_elems + block - 1) / block;
        feconv_elem_kernel<<<grid, block, 0, stream>>>(
            U, Kf, types, nodIdx, KU, n_elems);
    }
}

// Round 6
// 222.963 us; speedup vs baseline: 1.2303x; 1.2303x over previous
//
#include <hip/hip_runtime.h>
#include <hip/hip_fp16.h>

// FEM stiffness matvec KU = sum_e scatter(K_type(e) @ gather(U, e)).
//
// Round 20 = R16 structure + fp16 LDS filters -> TWO independent 512-thread
// blocks per CU (decorrelated barriers), EPT 2, CHUNK 1024, grid 489.
// R19 post-mortem (131 us): VGPR law ~= 256/(waves per EU). (1024,8) forced
// the ~70-reg EPT2 body into 32 regs -> spill disaster (FETCH/WRITE +100MB
// each). LESSON: occupancy must come from co-resident BLOCKS, not more
// resident threads; body needs cap >= ~56 -> max 4 waves/EU.
// R20 mechanism: R16's 16 waves all stall at the SAME 3 barriers (whole-CU
// idle at each drain). Two independent blocks/CU keep 16 waves but overlap
// one block's pass-C compute with the other's gather/barrier phases (m114:
// independent waves overlap pipes). Enabler: fp16 filter table = 64 types
// x 584 halves (8-half pad staggers banks: t*292 mod 32 = 4t) = 74,752 B
// + sort/bucket 6,656 B = 81,408 <= 81,920 -> exactly 2 blocks/CU.
// launch_bounds(512,4): cap 64 >= body ~56 -> NO spill. fp16 K error
// (2^-11) << bf16 U error (2^-8) already present -> absmax stays ~0.25.
// CHUNK 1024 + EPT 2: record runs 134 B (R18 showed 512-elem blocks
// fragment writes), grid 489 fills all 256 CUs (R16: 245 blocks, 11 idle).
// Carries: R17 block-local sort (uniform LDS reads, ~4 types/wave),
// early gather issue, bf16-packed U, 8 B records, block tail reservation,
// K2_TPB 1024. R15: never permute elements globally. ~110 us harness fixed.

#define NTYPES    64
#define KHALF     584            // halves per type: 1168 B stride, banks 4t mod 32
#define RSHIFT    11
#define RNODES    2048
#define MAXB      512
#define CAP       10240          // mean 8180/bucket, huge slack (even: 16 B pairs)
#define K1_TPB    512
#define K1_EPT    2
#define K1_CHUNK  (K1_TPB * K1_EPT)   // 1024
#define K2_TPB    1024
#define PREP_TPB  256

typedef int          nint4  __attribute__((ext_vector_type(4)));
typedef unsigned int nuint2 __attribute__((ext_vector_type(2)));
typedef unsigned int nuint4 __attribute__((ext_vector_type(4)));

__device__ __forceinline__ unsigned bf16_rne(float f) {
    unsigned b = __float_as_uint(f);
    return (b + 0x7FFFu + ((b >> 16) & 1u)) >> 16;
}

__device__ __forceinline__ float2 h2f(unsigned h) {
    __half2 x = *reinterpret_cast<__half2*>(&h);
    return __half22float2(x);
}

// ---- phase 0: pack U -> bf16 triples; zero KU and tails -------------------

__global__ __launch_bounds__(PREP_TPB) void pack_u_kernel(
    const float* __restrict__ U, nuint2* __restrict__ Ub,
    float* __restrict__ KU, unsigned* __restrict__ tails,
    int n_nodes, int n_buckets)
{
    int n = blockIdx.x * PREP_TPB + threadIdx.x;
    if (n < n_buckets) tails[n] = 0;
    if (n >= n_nodes) return;
    const float* up = U + (size_t)n * 3;
    unsigned bx = bf16_rne(up[0]);
    unsigned by = bf16_rne(up[1]);
    unsigned bz = bf16_rne(up[2]);
    nuint2 v = { bx | (by << 16), bz };
    Ub[n] = v;
    KU[3 * n + 0] = 0.f;
    KU[3 * n + 1] = 0.f;
    KU[3 * n + 2] = 0.f;
}

// ---- phase 1: compute + bin (fp16 filters, 2 blocks/CU, local sort) ------

__global__ __launch_bounds__(K1_TPB, 4) void feconv_bin_kernel(
    const nuint2* __restrict__ Ub,      // [N] packed bf16 x,y,z
    const float* __restrict__ K,        // [64, 24, 24]
    const int*   __restrict__ types,    // [E]
    const int*   __restrict__ nodIdx,   // [E, 8]
    float*       __restrict__ KU,       // overflow fallback only
    unsigned*    __restrict__ tails,    // [n_buckets]
    nuint2*      __restrict__ recs,     // [n_buckets * CAP]
    int n_elems, int n_buckets)
{
    extern __shared__ __half sKh[];            // [64 * KHALF] = 74,752 B
    __shared__ unsigned       sCnt[MAXB];      // 2 KB
    __shared__ unsigned       sBase[MAXB];     // 2 KB
    __shared__ unsigned       sTCnt[NTYPES];   // 256 B
    __shared__ unsigned       sTOff[NTYPES];   // 256 B
    __shared__ unsigned short sOrder[K1_CHUNK];// 2 KB: li | (type<<10)

    // stage filters fp32 -> fp16 (coalesced reads, scalar b16 LDS writes)
    for (int w = threadIdx.x; w < NTYPES * 576; w += K1_TPB) {
        int t = w / 576;
        int r = w - t * 576;
        sKh[t * KHALF + r] = __float2half(K[w]);
    }
    for (int i = threadIdx.x; i < n_buckets; i += K1_TPB) sCnt[i] = 0;
    if (threadIdx.x < NTYPES) sTCnt[threadIdx.x] = 0;
    __syncthreads();

    const int base = blockIdx.x * K1_CHUNK;
    int cnt_chunk = n_elems - base;
    if (cnt_chunk > K1_CHUNK) cnt_chunk = K1_CHUNK;

    // S0: coalesced type load + per-type count
    int myT[K1_EPT];
#pragma unroll
    for (int k = 0; k < K1_EPT; ++k) {
        int li = threadIdx.x + k * K1_TPB;
        myT[k] = -1;
        if (li < cnt_chunk) {
            int t = __builtin_nontemporal_load(&types[base + li]);
            myT[k] = t;
            atomicAdd(&sTCnt[t], 1u);
        }
    }
    __syncthreads();

    // S1: exclusive prefix scan over 64 type counts (wave 0 shfl scan)
    if (threadIdx.x < NTYPES) {
        unsigned v = sTCnt[threadIdx.x];
        unsigned s = v;
#pragma unroll
        for (int d = 1; d < NTYPES; d <<= 1) {
            unsigned o = __shfl_up(s, d, 64);
            if ((int)threadIdx.x >= d) s += o;
        }
        sTOff[threadIdx.x] = s - v;
        sTCnt[threadIdx.x] = 0;          // reuse as placement cursor
    }
    __syncthreads();

    // S2: scatter into type-sorted order (packed: li | type<<10)
#pragma unroll
    for (int k = 0; k < K1_EPT; ++k) {
        if (myT[k] >= 0) {
            int li = threadIdx.x + k * K1_TPB;
            unsigned p = sTOff[myT[k]] + atomicAdd(&sTCnt[myT[k]], 1u);
            sOrder[p] = (unsigned short)(li | (myT[k] << 10));
        }
    }
    __syncthreads();

    int    tt[K1_EPT];
    int    nodes[K1_EPT][8];
    nuint2 uu[K1_EPT][8];               // in-flight packed gathers

    // pass A: (sorted) connectivity + EARLY gather issue + bucket count.
    // nodIdx reads stay inside this block's 32 KB window (lines fully
    // consumed by this block -> DRAM pattern ~sequential).
#pragma unroll
    for (int k = 0; k < K1_EPT; ++k) {
        int slot = threadIdx.x + k * K1_TPB;
        tt[k] = -1;
        if (slot < cnt_chunk) {
            unsigned od = sOrder[slot];
            int li  = od & (K1_CHUNK - 1);
            tt[k]   = od >> 10;
            int e   = base + li;
            const nint4* q = (const nint4*)(nodIdx + (size_t)e * 8);
            nint4 a = q[0];
            nint4 b = q[1];
            nodes[k][0] = a.x; nodes[k][1] = a.y; nodes[k][2] = a.z; nodes[k][3] = a.w;
            nodes[k][4] = b.x; nodes[k][5] = b.y; nodes[k][6] = b.z; nodes[k][7] = b.w;
#pragma unroll
            for (int j = 0; j < 8; ++j)
                uu[k][j] = Ub[nodes[k][j]];
#pragma unroll
            for (int j = 0; j < 8; ++j)
                atomicAdd(&sCnt[(unsigned)nodes[k][j] >> RSHIFT], 1u);
        }
    }
    __syncthreads();

    // pass B: one global tail reservation per (block, bucket)
    for (int b = threadIdx.x; b < n_buckets; b += K1_TPB) {
        unsigned c = sCnt[b];
        sBase[b] = c ? atomicAdd(&tails[b], c) : 0u;
        sCnt[b] = 0;                     // reuse as local cursor
    }
    __syncthreads();

    // pass C: unpack, matvec; sorted order -> ~4 types/wave LDS broadcasts
#pragma unroll
    for (int k = 0; k < K1_EPT; ++k) {
        if (tt[k] < 0) continue;

        float ue[24];
#pragma unroll
        for (int j = 0; j < 8; ++j) {
            nuint2 v = uu[k][j];
            ue[3 * j + 0] = __uint_as_float(v.x << 16);
            ue[3 * j + 1] = __uint_as_float(v.x & 0xFFFF0000u);
            ue[3 * j + 2] = __uint_as_float(v.y << 16);
        }

        // row r starts at half-index tt*KHALF + r*24; (r,q) pair -> nuint2
        // index r*6 + q (8-B aligned), 4 halves per read (ds_read_b64)
        const nuint2* KtQ = (const nuint2*)(sKh + (size_t)tt[k] * KHALF);
#pragma unroll
        for (int j = 0; j < 8; ++j) {
            float a0 = 0.f, a1 = 0.f, a2 = 0.f;
#pragma unroll
            for (int q = 0; q < 6; ++q) {
                nuint2 k0 = KtQ[(3 * j + 0) * 6 + q];
                nuint2 k1 = KtQ[(3 * j + 1) * 6 + q];
                nuint2 k2 = KtQ[(3 * j + 2) * 6 + q];
                float u0 = ue[4 * q + 0], u1 = ue[4 * q + 1];
                float u2 = ue[4 * q + 2], u3 = ue[4 * q + 3];
                float2 f0a = h2f(k0.x), f0b = h2f(k0.y);
                float2 f1a = h2f(k1.x), f1b = h2f(k1.y);
                float2 f2a = h2f(k2.x), f2b = h2f(k2.y);
                a0 += f0a.x * u0 + f0a.y * u1 + f0b.x * u2 + f0b.y * u3;
                a1 += f1a.x * u0 + f1a.y * u1 + f1b.x * u2 + f1b.y * u3;
                a2 += f2a.x * u0 + f2a.y * u1 + f2b.x * u2 + f2b.y * u3;
            }
            unsigned n = (unsigned)nodes[k][j];
            unsigned b = n >> RSHIFT;
            unsigned pos = sBase[b] + atomicAdd(&sCnt[b], 1u);
            if (pos < CAP) {
                unsigned local = n & (RNODES - 1);
                nuint2 r = { bf16_rne(a0) | (bf16_rne(a1) << 16),
                             bf16_rne(a2) | (local << 16) };
                recs[(size_t)b * CAP + pos] = r;
            } else {  // statistically unreachable; absolute correctness
                atomicAdd(&KU[(size_t)n * 3 + 0], a0);
                atomicAdd(&KU[(size_t)n * 3 + 1], a1);
                atomicAdd(&KU[(size_t)n * 3 + 2], a2);
            }
        }
    }
}

// ---- phase 2: accumulate per bucket --------------------------------------

__global__ __launch_bounds__(K2_TPB) void feconv_acc_kernel(
    const nuint2*   __restrict__ recs,
    const unsigned* __restrict__ tails,
    float*          __restrict__ KU,     // [N, 3], pre-zeroed
    int n_nodes)
{
    __shared__ float sAcc[RNODES * 3];   // 24 KB; TPB 1024 -> 2 blocks/CU
    const int b = blockIdx.x;

    for (int i = threadIdx.x; i < RNODES * 3; i += K2_TPB) sAcc[i] = 0.f;
    __syncthreads();

    unsigned cnt = tails[b];
    if (cnt > CAP) cnt = CAP;
    const nuint2* base = recs + (size_t)b * CAP;
    const nuint4* base4 = (const nuint4*)base;       // 16 B-aligned (CAP even)

    unsigned npairs = cnt >> 1;
    for (unsigned i = threadIdx.x; i < npairs; i += K2_TPB) {
        nuint4 p = base4[i];                          // two records, one load
        unsigned o0 = (p.y >> 16) * 3;
        atomicAdd(&sAcc[o0 + 0], __uint_as_float(p.x << 16));
        atomicAdd(&sAcc[o0 + 1], __uint_as_float(p.x & 0xFFFF0000u));
        atomicAdd(&sAcc[o0 + 2], __uint_as_float(p.y << 16));
        unsigned o1 = (p.w >> 16) * 3;
        atomicAdd(&sAcc[o1 + 0], __uint_as_float(p.z << 16));
        atomicAdd(&sAcc[o1 + 1], __uint_as_float(p.z & 0xFFFF0000u));
        atomicAdd(&sAcc[o1 + 2], __uint_as_float(p.w << 16));
    }
    if ((cnt & 1u) && threadIdx.x == 0) {             // odd tail record
        nuint2 r = base[cnt - 1];
        unsigned o = (r.y >> 16) * 3;
        atomicAdd(&sAcc[o + 0], __uint_as_float(r.x << 16));
        atomicAdd(&sAcc[o + 1], __uint_as_float(r.x & 0xFFFF0000u));
        atomicAdd(&sAcc[o + 2], __uint_as_float(r.y << 16));
    }
    __syncthreads();

    const int nbase = b * RNODES;
    int limit = n_nodes - nbase;
    if (limit > RNODES) limit = RNODES;
    limit *= 3;
    float* out = KU + (size_t)nbase * 3;
    for (int i = threadIdx.x; i < limit; i += K2_TPB) out[i] += sAcc[i];
}

// ---- fallback (round-0 style) --------------------------------------------

__global__ __launch_bounds__(256) void feconv_elem_kernel(
    const float* __restrict__ U, const float* __restrict__ K,
    const int* __restrict__ types, const int* __restrict__ nodIdx,
    float* __restrict__ KU, int n_elems)
{
    int e = blockIdx.x * blockDim.x + threadIdx.x;
    if (e >= n_elems) return;
    int t = types[e];
    const int4* idx4 = (const int4*)(nodIdx + (size_t)e * 8);
    int4 iA = idx4[0], iB = idx4[1];
    int nodes[8] = {iA.x, iA.y, iA.z, iA.w, iB.x, iB.y, iB.z, iB.w};
    float ue[24];
#pragma unroll
    for (int j = 0; j < 8; ++j) {
        const float* up = U + (size_t)nodes[j] * 3;
        ue[3 * j + 0] = up[0]; ue[3 * j + 1] = up[1]; ue[3 * j + 2] = up[2];
    }
    const float* Kt = K + (size_t)t * 576;
#pragma unroll
    for (int i = 0; i < 24; ++i) {
        const float4* row = (const float4*)(Kt + i * 24);
        float acc = 0.f;
#pragma unroll
        for (int q = 0; q < 6; ++q) {
            float4 k = row[q];
            acc += k.x * ue[4 * q + 0] + k.y * ue[4 * q + 1]
                 + k.z * ue[4 * q + 2] + k.w * ue[4 * q + 3];
        }
        atomicAdd(&KU[(size_t)nodes[i / 3] * 3 + (i % 3)], acc);
    }
}

extern "C" void kernel_launch(void* const* d_in, const int* in_sizes, int n_in,
                              void* d_out, int out_size, void* d_ws, size_t ws_size,
                              hipStream_t stream) {
    const float* U      = (const float*)d_in[0];
    const float* Kf     = (const float*)d_in[1];
    const int*   types  = (const int*)d_in[2];
    const int*   nodIdx = (const int*)d_in[3];
    float*       KU     = (float*)d_out;

    const int n_elems = in_sizes[2];
    const int n_nodes = in_sizes[0] / 3;
    const int n_buckets = (n_nodes + RNODES - 1) / RNODES;   // 489 for N=1M

    // ws layout: [0, 4096) tails | [4096, +8B*n_nodes) Ub | then recs
    const size_t ub_off  = 4096;
    const size_t rec_off = ub_off + (((size_t)n_nodes * 8 + 255) & ~255ull);
    const size_t need    = rec_off + (size_t)n_buckets * CAP * 8;

    if (n_buckets <= MAXB && ws_size >= need) {
        unsigned* tails = (unsigned*)d_ws;
        nuint2*   Ub    = (nuint2*)((char*)d_ws + ub_off);
        nuint2*   recs  = (nuint2*)((char*)d_ws + rec_off);

        int gridP = (n_nodes + PREP_TPB - 1) / PREP_TPB;
        pack_u_kernel<<<gridP, PREP_TPB, 0, stream>>>(
            U, Ub, KU, tails, n_nodes, n_buckets);

        size_t lds_bytes = (size_t)NTYPES * KHALF * sizeof(__half); // 74,752
        int grid1 = (n_elems + K1_CHUNK - 1) / K1_CHUNK;            // 489
        feconv_bin_kernel<<<grid1, K1_TPB, lds_bytes, stream>>>(
            Ub, Kf, types, nodIdx, KU, tails, recs, n_elems, n_buckets);
        feconv_acc_kernel<<<n_buckets, K2_TPB, 0, stream>>>(
            recs, tails, KU, n_nodes);
    } else {
        (void)hipMemsetAsync(KU, 0, (size_t)out_size * sizeof(float), stream);
        int block = 256;
        int grid = (n_elems + block - 1) / block;
        feconv_elem_kernel<<<grid, block, 0, stream>>>(
            U, Kf, types, nodIdx, KU, n_elems);
    }
}

// Round 7
// 220.769 us; speedup vs baseline: 1.2425x; 1.0099x over previous
//
#include <hip/hip_runtime.h>
#include <hip/hip_fp16.h>

// FEM stiffness matvec KU = sum_e scatter(K_type(e) @ gather(U, e)).
//
// Round 21 = EXACT R16 structure (212.0 us; K1 71.5 us) + fp16 filter path.
// R20 post-mortem (K1 84 us): 2nd 79.5KB block did NOT co-reside (occupancy
// 31.6% ~= 8-10 waves) -> "2 blocks/CU via big-LDS halving" infeasible; and
// the R17 sort costs +20-34MB FETCH (randomizes Ub gather order) -> DROPPED.
// Data fact: nodIdx is UNIFORM RANDOM (no mesh locality) -> XCD swizzle /
// node-order schemes are dead ends; 4M random 8B gathers are irreducible;
// R16's 16 waves/CU (1024thr, 1 blk/CU) is the best hiding config found.
// R21 mechanism: shrink work on the two busiest pipes, same structure:
//  - fp16 LDS filters: 144 reads/elem go b128->b64 (bytes and bank touches
//    halve; R16 LDS term ~82K cyc/CU incl 29.5K conflicts -> ~40K).
//  - v_dot2_f32_f16: 576 FMA -> 288 fdot2 + ~36 cvt (fp16 products exact
//    in f32; bf16->fp16 of U exact). VALU -40%.
//  - staging halves (147->74KB LDS writes).
// Precision: absmax driven by bf16 record quantization (2^-8); fp16 K adds
// 2^-11 rel -> absmax stays ~0.25.
// VGPR law (R19): cap = 256/(waves/EU); (1024,4) cap 64 >= body ~52. R10/R19:
// never cap below body. Carries: EPT2 early gather issue, bf16-packed U,
// 8B records, block tail reservation, K2_TPB 1024 (R16 +3.5us), NO sort.
// ~110 us of total is harness fixed (R13).

#define NTYPES    64
#define KHALF     584            // halves per type: 1168 B stride (8B-aligned)
#define RSHIFT    11
#define RNODES    2048
#define MAXB      512
#define CAP       10240          // mean 8180/bucket, huge slack (even: 16 B pairs)
#define K1_TPB    1024
#define K1_EPT    2
#define K1_CHUNK  (K1_TPB * K1_EPT)
#define K2_TPB    1024
#define PREP_TPB  256

typedef int          nint4  __attribute__((ext_vector_type(4)));
typedef unsigned int nuint2 __attribute__((ext_vector_type(2)));
typedef unsigned int nuint4 __attribute__((ext_vector_type(4)));
typedef _Float16     half2v __attribute__((ext_vector_type(2)));

__device__ __forceinline__ unsigned bf16_rne(float f) {
    unsigned b = __float_as_uint(f);
    return (b + 0x7FFFu + ((b >> 16) & 1u)) >> 16;
}

__device__ __forceinline__ half2v as_h2(unsigned u) {
    return *reinterpret_cast<half2v*>(&u);
}

#if defined(__has_builtin)
#if __has_builtin(__builtin_amdgcn_fdot2)
#define HAVE_FDOT2 1
#endif
#endif

// ---- phase 0: pack U -> bf16 triples; zero KU and tails -------------------

__global__ __launch_bounds__(PREP_TPB) void pack_u_kernel(
    const float* __restrict__ U, nuint2* __restrict__ Ub,
    float* __restrict__ KU, unsigned* __restrict__ tails,
    int n_nodes, int n_buckets)
{
    int n = blockIdx.x * PREP_TPB + threadIdx.x;
    if (n < n_buckets) tails[n] = 0;
    if (n >= n_nodes) return;
    const float* up = U + (size_t)n * 3;
    unsigned bx = bf16_rne(up[0]);
    unsigned by = bf16_rne(up[1]);
    unsigned bz = bf16_rne(up[2]);
    nuint2 v = { bx | (by << 16), bz };
    Ub[n] = v;
    KU[3 * n + 0] = 0.f;
    KU[3 * n + 1] = 0.f;
    KU[3 * n + 2] = 0.f;
}

// ---- phase 1: compute + bin (fp16 filters + dot2) ------------------------

__global__ __launch_bounds__(K1_TPB, 4) void feconv_bin_kernel(
    const nuint2* __restrict__ Ub,      // [N] packed bf16 x,y,z
    const float* __restrict__ K,        // [64, 24, 24]
    const int*   __restrict__ types,    // [E]
    const int*   __restrict__ nodIdx,   // [E, 8]
    float*       __restrict__ KU,       // overflow fallback only
    unsigned*    __restrict__ tails,    // [n_buckets]
    nuint2*      __restrict__ recs,     // [n_buckets * CAP]
    int n_elems, int n_buckets)
{
    extern __shared__ __half sKh[];     // [64 * KHALF] = 74,752 B
    __shared__ unsigned sCnt[MAXB];
    __shared__ unsigned sBase[MAXB];

    // stage filters fp32 -> fp16 (coalesced global reads, b16 LDS writes)
    for (int w = threadIdx.x; w < NTYPES * 576; w += K1_TPB) {
        int t = w / 576;
        int r = w - t * 576;
        sKh[t * KHALF + r] = __float2half(K[w]);
    }
    for (int i = threadIdx.x; i < n_buckets; i += K1_TPB) sCnt[i] = 0;
    __syncthreads();

    const int e0 = blockIdx.x * K1_CHUNK + threadIdx.x;
    int     nodes[K1_EPT][8];
    int     tt[K1_EPT];
    nuint2  uu[K1_EPT][8];              // in-flight packed gathers

    // pass A: connectivity + EARLY gather issue + bucket counting
#pragma unroll
    for (int k = 0; k < K1_EPT; ++k) {
        int e = e0 + k * K1_TPB;
        tt[k] = -1;
        if (e < n_elems) {
            tt[k] = __builtin_nontemporal_load(&types[e]);
            const nint4* q = (const nint4*)(nodIdx + (size_t)e * 8);
            nint4 a = __builtin_nontemporal_load(q);
            nint4 b = __builtin_nontemporal_load(q + 1);
            nodes[k][0] = a.x; nodes[k][1] = a.y; nodes[k][2] = a.z; nodes[k][3] = a.w;
            nodes[k][4] = b.x; nodes[k][5] = b.y; nodes[k][6] = b.z; nodes[k][7] = b.w;
#pragma unroll
            for (int j = 0; j < 8; ++j)
                uu[k][j] = Ub[nodes[k][j]];          // issue all 16 gathers now
#pragma unroll
            for (int j = 0; j < 8; ++j)
                atomicAdd(&sCnt[(unsigned)nodes[k][j] >> RSHIFT], 1u);
        }
    }
    __syncthreads();

    // pass B: one global tail reservation per (block, bucket)
    for (int b = threadIdx.x; b < n_buckets; b += K1_TPB) {
        unsigned c = sCnt[b];
        sBase[b] = c ? atomicAdd(&tails[b], c) : 0u;
        sCnt[b] = 0;                     // reuse as local cursor
    }
    __syncthreads();

    // pass C: unpack to fp16 pairs, matvec via ds_read_b64 + v_dot2_f32_f16
#pragma unroll
    for (int k = 0; k < K1_EPT; ++k) {
        if (tt[k] < 0) continue;

        // ue pairs: ueh[2q] = (u[4q],u[4q+1]), ueh[2q+1] = (u[4q+2],u[4q+3])
        half2v ueh[12];
        {
            float uef[24];
#pragma unroll
            for (int j = 0; j < 8; ++j) {
                nuint2 v = uu[k][j];
                uef[3 * j + 0] = __uint_as_float(v.x << 16);
                uef[3 * j + 1] = __uint_as_float(v.x & 0xFFFF0000u);
                uef[3 * j + 2] = __uint_as_float(v.y << 16);
            }
#pragma unroll
            for (int p = 0; p < 12; ++p) {
                half2v h; h.x = (_Float16)uef[2 * p]; h.y = (_Float16)uef[2 * p + 1];
                ueh[p] = h;
            }
        }

        // row r: halves [t*KHALF + r*24, +24); (r,q) -> nuint2 idx r*6+q
        const nuint2* KtQ = (const nuint2*)(sKh + (size_t)tt[k] * KHALF);
#pragma unroll
        for (int j = 0; j < 8; ++j) {
            float a0 = 0.f, a1 = 0.f, a2 = 0.f;
#pragma unroll
            for (int q = 0; q < 6; ++q) {
                nuint2 k0 = KtQ[(3 * j + 0) * 6 + q];
                nuint2 k1 = KtQ[(3 * j + 1) * 6 + q];
                nuint2 k2 = KtQ[(3 * j + 2) * 6 + q];
#ifdef HAVE_FDOT2
                a0 = __builtin_amdgcn_fdot2(as_h2(k0.x), ueh[2 * q],     a0, false);
                a0 = __builtin_amdgcn_fdot2(as_h2(k0.y), ueh[2 * q + 1], a0, false);
                a1 = __builtin_amdgcn_fdot2(as_h2(k1.x), ueh[2 * q],     a1, false);
                a1 = __builtin_amdgcn_fdot2(as_h2(k1.y), ueh[2 * q + 1], a1, false);
                a2 = __builtin_amdgcn_fdot2(as_h2(k2.x), ueh[2 * q],     a2, false);
                a2 = __builtin_amdgcn_fdot2(as_h2(k2.y), ueh[2 * q + 1], a2, false);
#else
                half2v u01 = ueh[2 * q], u23 = ueh[2 * q + 1];
                half2v f0a = as_h2(k0.x), f0b = as_h2(k0.y);
                half2v f1a = as_h2(k1.x), f1b = as_h2(k1.y);
                half2v f2a = as_h2(k2.x), f2b = as_h2(k2.y);
                a0 += (float)f0a.x * (float)u01.x + (float)f0a.y * (float)u01.y
                    + (float)f0b.x * (float)u23.x + (float)f0b.y * (float)u23.y;
                a1 += (float)f1a.x * (float)u01.x + (float)f1a.y * (float)u01.y
                    + (float)f1b.x * (float)u23.x + (float)f1b.y * (float)u23.y;
                a2 += (float)f2a.x * (float)u01.x + (float)f2a.y * (float)u01.y
                    + (float)f2b.x * (float)u23.x + (float)f2b.y * (float)u23.y;
#endif
            }
            unsigned n = (unsigned)nodes[k][j];
            unsigned b = n >> RSHIFT;
            unsigned pos = sBase[b] + atomicAdd(&sCnt[b], 1u);
            if (pos < CAP) {
                unsigned local = n & (RNODES - 1);
                nuint2 r = { bf16_rne(a0) | (bf16_rne(a1) << 16),
                             bf16_rne(a2) | (local << 16) };
                recs[(size_t)b * CAP + pos] = r;
            } else {  // statistically unreachable; absolute correctness
                atomicAdd(&KU[(size_t)n * 3 + 0], a0);
                atomicAdd(&KU[(size_t)n * 3 + 1], a1);
                atomicAdd(&KU[(size_t)n * 3 + 2], a2);
            }
        }
    }
}

// ---- phase 2: accumulate per bucket --------------------------------------

__global__ __launch_bounds__(K2_TPB) void feconv_acc_kernel(
    const nuint2*   __restrict__ recs,
    const unsigned* __restrict__ tails,
    float*          __restrict__ KU,     // [N, 3], pre-zeroed
    int n_nodes)
{
    __shared__ float sAcc[RNODES * 3];   // 24 KB; TPB 1024 -> 2 blocks/CU
    const int b = blockIdx.x;

    for (int i = threadIdx.x; i < RNODES * 3; i += K2_TPB) sAcc[i] = 0.f;
    __syncthreads();

    unsigned cnt = tails[b];
    if (cnt > CAP) cnt = CAP;
    const nuint2* base = recs + (size_t)b * CAP;
    const nuint4* base4 = (const nuint4*)base;       // 16 B-aligned (CAP even)

    unsigned npairs = cnt >> 1;
    for (unsigned i = threadIdx.x; i < npairs; i += K2_TPB) {
        nuint4 p = base4[i];                          // two records, one load
        unsigned o0 = (p.y >> 16) * 3;
        atomicAdd(&sAcc[o0 + 0], __uint_as_float(p.x << 16));
        atomicAdd(&sAcc[o0 + 1], __uint_as_float(p.x & 0xFFFF0000u));
        atomicAdd(&sAcc[o0 + 2], __uint_as_float(p.y << 16));
        unsigned o1 = (p.w >> 16) * 3;
        atomicAdd(&sAcc[o1 + 0], __uint_as_float(p.z << 16));
        atomicAdd(&sAcc[o1 + 1], __uint_as_float(p.z & 0xFFFF0000u));
        atomicAdd(&sAcc[o1 + 2], __uint_as_float(p.w << 16));
    }
    if ((cnt & 1u) && threadIdx.x == 0) {             // odd tail record
        nuint2 r = base[cnt - 1];
        unsigned o = (r.y >> 16) * 3;
        atomicAdd(&sAcc[o + 0], __uint_as_float(r.x << 16));
        atomicAdd(&sAcc[o + 1], __uint_as_float(r.x & 0xFFFF0000u));
        atomicAdd(&sAcc[o + 2], __uint_as_float(r.y << 16));
    }
    __syncthreads();

    const int nbase = b * RNODES;
    int limit = n_nodes - nbase;
    if (limit > RNODES) limit = RNODES;
    limit *= 3;
    float* out = KU + (size_t)nbase * 3;
    for (int i = threadIdx.x; i < limit; i += K2_TPB) out[i] += sAcc[i];
}

// ---- fallback (round-0 style) --------------------------------------------

__global__ __launch_bounds__(256) void feconv_elem_kernel(
    const float* __restrict__ U, const float* __restrict__ K,
    const int* __restrict__ types, const int* __restrict__ nodIdx,
    float* __restrict__ KU, int n_elems)
{
    int e = blockIdx.x * blockDim.x + threadIdx.x;
    if (e >= n_elems) return;
    int t = types[e];
    const int4* idx4 = (const int4*)(nodIdx + (size_t)e * 8);
    int4 iA = idx4[0], iB = idx4[1];
    int nodes[8] = {iA.x, iA.y, iA.z, iA.w, iB.x, iB.y, iB.z, iB.w};
    float ue[24];
#pragma unroll
    for (int j = 0; j < 8; ++j) {
        const float* up = U + (size_t)nodes[j] * 3;
        ue[3 * j + 0] = up[0]; ue[3 * j + 1] = up[1]; ue[3 * j + 2] = up[2];
    }
    const float* Kt = K + (size_t)t * 576;
#pragma unroll
    for (int i = 0; i < 24; ++i) {
        const float4* row = (const float4*)(Kt + i * 24);
        float acc = 0.f;
#pragma unroll
        for (int q = 0; q < 6; ++q) {
            float4 k = row[q];
            acc += k.x * ue[4 * q + 0] + k.y * ue[4 * q + 1]
                 + k.z * ue[4 * q + 2] + k.w * ue[4 * q + 3];
        }
        atomicAdd(&KU[(size_t)nodes[i / 3] * 3 + (i % 3)], acc);
    }
}

extern "C" void kernel_launch(void* const* d_in, const int* in_sizes, int n_in,
                              void* d_out, int out_size, void* d_ws, size_t ws_size,
                              hipStream_t stream) {
    const float* U      = (const float*)d_in[0];
    const float* Kf     = (const float*)d_in[1];
    const int*   types  = (const int*)d_in[2];
    const int*   nodIdx = (const int*)d_in[3];
    float*       KU     = (float*)d_out;

    const int n_elems = in_sizes[2];
    const int n_nodes = in_sizes[0] / 3;
    const int n_buckets = (n_nodes + RNODES - 1) / RNODES;   // 489 for N=1M

    // ws layout: [0, 4096) tails | [4096, +8B*n_nodes) Ub | then recs
    const size_t ub_off  = 4096;
    const size_t rec_off = ub_off + (((size_t)n_nodes * 8 + 255) & ~255ull);
    const size_t need    = rec_off + (size_t)n_buckets * CAP * 8;

    if (n_buckets <= MAXB && ws_size >= need) {
        unsigned* tails = (unsigned*)d_ws;
        nuint2*   Ub    = (nuint2*)((char*)d_ws + ub_off);
        nuint2*   recs  = (nuint2*)((char*)d_ws + rec_off);

        int gridP = (n_nodes + PREP_TPB - 1) / PREP_TPB;
        pack_u_kernel<<<gridP, PREP_TPB, 0, stream>>>(
            U, Ub, KU, tails, n_nodes, n_buckets);

        size_t lds_bytes = (size_t)NTYPES * KHALF * sizeof(__half);  // 74,752
        int grid1 = (n_elems + K1_CHUNK - 1) / K1_CHUNK;             // 245
        feconv_bin_kernel<<<grid1, K1_TPB, lds_bytes, stream>>>(
            Ub, Kf, types, nodIdx, KU, tails, recs, n_elems, n_buckets);
        feconv_acc_kernel<<<n_buckets, K2_TPB, 0, stream>>>(
            recs, tails, KU, n_nodes);
    } else {
        (void)hipMemsetAsync(KU, 0, (size_t)out_size * sizeof(float), stream);
        int block = 256;
        int grid = (n_elems + block - 1) / block;
        feconv_elem_kernel<<<grid, block, 0, stream>>>(
            U, Kf, types, nodIdx, KU, n_elems);
    }
}